// Round 3
// baseline (5468.187 us; speedup 1.0000x reference)
//
#include <hip/hip_runtime.h>
#include <hip/hip_bf16.h>

typedef __hip_bfloat16 bf16;
typedef unsigned short u16;

constexpr int CB = 2;     // batch
constexpr int CL = 2048;  // seq len
constexpr int CD = 1024;  // d_model
constexpr int CH = 16;    // heads
constexpr int CDH = 64;   // head dim
constexpr size_t OUT_ELEMS = (size_t)CB * CL * CD;   // offset of attn region in d_out

// ---- scratch in device globals (f32 end-to-end for max fidelity) ----
__device__ int   g_flag;                                    // 0 = bf16 inputs, 1 = f32 inputs
__device__ __align__(16) float g_qkvraw[(size_t)CB * CL * 3 * CD];      // [B*L][3072], e = sel*1024 + h*64 + d
__device__ __align__(16) float g_phase [(size_t)CB * CH * CL];          // [B*H][L]
__device__ __align__(16) float g_scores[(size_t)CB * CH * CL * CL];     // [B*H][Lq][Lk] (537 MB)
__device__ __align__(16) float g_otmp  [(size_t)CB * CL * CD];          // [B*L][D]

__device__ __forceinline__ float us2f(u16 u) {
    union { unsigned int i; float f; } x;
    x.i = ((unsigned int)u) << 16;
    return x.f;
}

template<int DT>
__device__ __forceinline__ float ld1(const void* p, size_t i) {
    if (DT == 0) return us2f(((const u16*)p)[i]);
    return ((const float*)p)[i];
}

template<int DT>
__device__ __forceinline__ void st1(void* p, size_t i, float v) {
    if (DT == 0) ((bf16*)p)[i] = __float2bfloat16(v);
    else         ((float*)p)[i] = v;
}

__global__ void detect_kernel(const void* ps) {
    // phase_scale == 1.0: bf16 -> first u16 is 0x3F80; f32 -> first u16 is 0x0000
    g_flag = (((const u16*)ps)[0] == 0x3F80) ? 0 : 1;
}

// ---------------- QKV projection: g_qkvraw[m][n] = sum_k x[m][k]*qkv_w[n][k] + qkv_b[n]
template<int DT>
__global__ __launch_bounds__(256) void qkv_gemm(const void* __restrict__ x,
                                                const void* __restrict__ w,
                                                const void* __restrict__ bias)
{
    if (g_flag != DT) return;
    __shared__ float As[16][17];
    __shared__ float Ws[16][17];
    const int tid = threadIdx.x;
    const int ty = tid >> 4, tx = tid & 15;
    const int m = blockIdx.y * 16 + ty;      // 0..4095
    const int n0 = blockIdx.x * 16;          // 0..3056
    const int n = n0 + tx;
    float acc = 0.f;
    for (int k0 = 0; k0 < CD; k0 += 16) {
        As[ty][tx] = ld1<DT>(x, (size_t)m * CD + k0 + tx);
        Ws[ty][tx] = ld1<DT>(w, (size_t)(n0 + ty) * CD + k0 + tx);
        __syncthreads();
        #pragma unroll
        for (int kk = 0; kk < 16; ++kk)
            acc = fmaf(As[ty][kk], Ws[tx][kk], acc);
        __syncthreads();
    }
    acc += ld1<DT>(bias, n);
    g_qkvraw[(size_t)m * (3 * CD) + n] = acc;
}

// ---------------- phase: g_phase[(b*16+h)*L + l] = tanh(ps*(x[b,l,:]·pw[h,:] + pb[h]))
template<int DT>
__global__ __launch_bounds__(256) void phase_k(const void* __restrict__ x,
                                               const void* __restrict__ pw,
                                               const void* __restrict__ pb,
                                               const void* __restrict__ ps)
{
    if (g_flag != DT) return;
    const int t = blockIdx.x * 256 + threadIdx.x;   // 0..65535
    const int row = t >> 4;                         // b*L + l
    const int h = t & 15;
    float s = 0.f;
    for (int d = 0; d < CD; ++d)
        s = fmaf(ld1<DT>(x, (size_t)row * CD + d), ld1<DT>(pw, (size_t)h * CD + d), s);
    s += ld1<DT>(pb, h);
    const float sc = ld1<DT>(ps, 0);
    const int b = row >> 11, l = row & (CL - 1);
    g_phase[((size_t)b * CH + h) * CL + l] = tanhf(sc * s);
}

// ---------------- scores: g_scores[bh][q][k] = q·k/8 - rs*(pv[q]-pv[k])^2
template<int DT>
__global__ __launch_bounds__(256) void scores_k(const void* __restrict__ rs_ptr)
{
    if (g_flag != DT) return;
    const int bh = blockIdx.z;            // b*16 + h
    const int b = bh >> 4, h = bh & 15;
    const int q0 = blockIdx.y * 16;
    const int k0 = blockIdx.x * 16;
    __shared__ float Qs[16][65];
    __shared__ float Ks[16][65];
    const int tid = threadIdx.x;
    for (int idx = tid; idx < 16 * 64; idx += 256) {
        const int r = idx >> 6, c = idx & 63;
        Qs[r][c] = g_qkvraw[(size_t)(b * CL + q0 + r) * (3 * CD) + 0 * CD + h * CDH + c];
        Ks[r][c] = g_qkvraw[(size_t)(b * CL + k0 + r) * (3 * CD) + 1 * CD + h * CDH + c];
    }
    __syncthreads();
    const int ty = tid >> 4, tx = tid & 15;   // ty: q row, tx: k col
    float s = 0.f;
    #pragma unroll 8
    for (int d = 0; d < CDH; ++d)
        s = fmaf(Qs[ty][d], Ks[tx][d], s);
    const float rs = ld1<DT>(rs_ptr, 0);
    const float pq = g_phase[(size_t)bh * CL + q0 + ty];
    const float pk = g_phase[(size_t)bh * CL + k0 + tx];
    const float dphi = pq - pk;
    g_scores[((size_t)bh * CL + q0 + ty) * CL + k0 + tx] = s * 0.125f - rs * dphi * dphi;
}

// ---------------- softmax per row; writes bf16/f32 weights to d_out attn region AND f32 back to g_scores
template<int DT>
__global__ __launch_bounds__(256) void softmax_k(void* __restrict__ d_out)
{
    if (g_flag != DT) return;
    const size_t base = (size_t)blockIdx.x * CL;   // blockIdx.x = bh*L + q, 0..65535
    const int tid = threadIdx.x;
    __shared__ float red[256];
    float m = -1e30f;
    for (int k = tid; k < CL; k += 256) m = fmaxf(m, g_scores[base + k]);
    red[tid] = m;
    __syncthreads();
    for (int s = 128; s > 0; s >>= 1) {
        if (tid < s) red[tid] = fmaxf(red[tid], red[tid + s]);
        __syncthreads();
    }
    const float M = red[0];
    __syncthreads();
    float sum = 0.f;
    for (int k = tid; k < CL; k += 256) {
        const float p = __expf(g_scores[base + k] - M);
        g_scores[base + k] = p;
        sum += p;
    }
    red[tid] = sum;
    __syncthreads();
    for (int s = 128; s > 0; s >>= 1) {
        if (tid < s) red[tid] += red[tid + s];
        __syncthreads();
    }
    const float inv = 1.f / red[0];
    __syncthreads();
    for (int k = tid; k < CL; k += 256) {
        const float p = g_scores[base + k] * inv;
        g_scores[base + k] = p;
        st1<DT>(d_out, OUT_ELEMS + base + k, p);
    }
}

// ---------------- PV: g_otmp[(b*L+q)*D + h*64 + d] = sum_k P[bh][q][k] * v[b][k][h*64+d]
__global__ __launch_bounds__(256) void pv_k()
{
    const int bh = blockIdx.z;
    const int b = bh >> 4, h = bh & 15;
    const int q0 = blockIdx.y * 16;
    const int d0 = blockIdx.x * 16;
    __shared__ float Ps[16][17];
    __shared__ float Vs[16][17];
    const int tid = threadIdx.x;
    const int ty = tid >> 4, tx = tid & 15;   // ty: q row, tx: d col
    float acc = 0.f;
    for (int k0 = 0; k0 < CL; k0 += 16) {
        Ps[ty][tx] = g_scores[((size_t)bh * CL + q0 + ty) * CL + k0 + tx];
        Vs[ty][tx] = g_qkvraw[(size_t)(b * CL + k0 + ty) * (3 * CD) + 2 * CD + h * CDH + d0 + tx];
        __syncthreads();
        #pragma unroll
        for (int kk = 0; kk < 16; ++kk)
            acc = fmaf(Ps[ty][kk], Vs[kk][tx], acc);
        __syncthreads();
    }
    g_otmp[(size_t)(b * CL + q0 + ty) * CD + h * CDH + d0 + tx] = acc;
}

// ---------------- out projection: d_out[m][n] = sum_k otmp[m][k]*out_w[n][k] + out_b[n]
template<int DT>
__global__ __launch_bounds__(256) void out_gemm(const void* __restrict__ w,
                                                const void* __restrict__ bias,
                                                void* __restrict__ d_out)
{
    if (g_flag != DT) return;
    __shared__ float As[16][17];
    __shared__ float Ws[16][17];
    const int tid = threadIdx.x;
    const int ty = tid >> 4, tx = tid & 15;
    const int m = blockIdx.y * 16 + ty;
    const int n0 = blockIdx.x * 16;
    const int n = n0 + tx;
    float acc = 0.f;
    for (int k0 = 0; k0 < CD; k0 += 16) {
        As[ty][tx] = g_otmp[(size_t)m * CD + k0 + tx];
        Ws[ty][tx] = ld1<DT>(w, (size_t)(n0 + ty) * CD + k0 + tx);
        __syncthreads();
        #pragma unroll
        for (int kk = 0; kk < 16; ++kk)
            acc = fmaf(As[ty][kk], Ws[tx][kk], acc);
        __syncthreads();
    }
    acc += ld1<DT>(bias, n);
    st1<DT>(d_out, (size_t)m * CD + n, acc);
}

extern "C" void kernel_launch(void* const* d_in, const int* in_sizes, int n_in,
                              void* d_out, int out_size, void* d_ws, size_t ws_size,
                              hipStream_t stream) {
    (void)in_sizes; (void)n_in; (void)out_size; (void)d_ws; (void)ws_size;
    const void* x       = d_in[0];
    const void* qkv_w   = d_in[1];
    const void* qkv_b   = d_in[2];
    const void* out_w   = d_in[3];
    const void* out_b   = d_in[4];
    const void* phase_w = d_in[5];
    const void* phase_b = d_in[6];
    const void* rs      = d_in[7];
    const void* ps      = d_in[8];

    dim3 blk(256);
    detect_kernel<<<1, 1, 0, stream>>>(ps);

    // QKV projection: M=4096, N=3072
    qkv_gemm<0><<<dim3(192, 256), blk, 0, stream>>>(x, qkv_w, qkv_b);
    qkv_gemm<1><<<dim3(192, 256), blk, 0, stream>>>(x, qkv_w, qkv_b);

    // phase: 65536 dot products
    phase_k<0><<<dim3(256), blk, 0, stream>>>(x, phase_w, phase_b, ps);
    phase_k<1><<<dim3(256), blk, 0, stream>>>(x, phase_w, phase_b, ps);

    // scores: per (b,h) 2048x2048
    scores_k<0><<<dim3(128, 128, 32), blk, 0, stream>>>(rs);
    scores_k<1><<<dim3(128, 128, 32), blk, 0, stream>>>(rs);

    // softmax: one block per (bh, q) row
    softmax_k<0><<<dim3(65536), blk, 0, stream>>>(d_out);
    softmax_k<1><<<dim3(65536), blk, 0, stream>>>(d_out);

    // PV (dtype-independent: pure f32 scratch)
    pv_k<<<dim3(4, 128, 32), blk, 0, stream>>>();

    // out projection: M=4096, N=1024
    out_gemm<0><<<dim3(64, 256), blk, 0, stream>>>(out_w, out_b, d_out);
    out_gemm<1><<<dim3(64, 256), blk, 0, stream>>>(out_w, out_b, d_out);
}